// Round 9
// baseline (132.311 us; speedup 1.0000x reference)
//
#include <hip/hip_runtime.h>
#include <math.h>

typedef __attribute__((ext_vector_type(8))) _Float16 half8;
typedef __attribute__((ext_vector_type(4))) _Float16 half4;
typedef __attribute__((ext_vector_type(4))) float    f32x4;

#define TSTEPS 28
#define IDIM   28
#define HDIM   128
#define NKC    5       // K chunks of 32: 160 = 128 (h) + 28 (x) + bias(1) + 3 pad
#define TILE_B 16
#define CDIM   10

#if __has_builtin(__builtin_amdgcn_exp2f)
#define EXP2F(x) __builtin_amdgcn_exp2f(x)
#else
#define EXP2F(x) exp2f(x)
#endif
#if __has_builtin(__builtin_amdgcn_rcpf)
#define RCPF(x) __builtin_amdgcn_rcpf(x)
#else
#define RCPF(x) (1.0f / (x))
#endif

#define NLOG2E (-1.44269504f)
#define P2LOG2E (2.88539008f)

// P[kc][t][w][lane][j] (f16): B-fragment order for mfma_f32_16x16x32_f16.
// Activation scales folded (i,f,o x -log2e; g x 2log2e). Bias row at k=156
// (pairs with constant 1.0 in A column 156). k=157..159 zero.
__global__ __launch_bounds__(256) void pack_w(const float* __restrict__ Wih,
                                              const float* __restrict__ Whh,
                                              const float* __restrict__ bih,
                                              const float* __restrict__ bhh,
                                              _Float16* __restrict__ P) {
    int e = blockIdx.x * 256 + threadIdx.x;      // 5*4*8*64*8 = 81920
    if (e >= NKC * 4 * 8 * 64 * 8) return;
    int j  = e & 7;
    int ln = (e >> 3) & 63;
    int w  = (e >> 9) & 7;
    int t  = (e >> 12) & 3;
    int kc = e >> 14;
    int k  = kc * 32 + ((ln >> 4) << 3) + j;
    int u  = w * 16 + (ln & 15);
    int g  = t * HDIM + u;
    float v = 0.f;
    if (k < HDIM)                   v = Whh[g * HDIM + k];
    else if (k < HDIM + IDIM)       v = Wih[g * IDIM + (k - HDIM)];
    else if (k == HDIM + IDIM)      v = bih[g] + bhh[g];   // bias row
    float sc = (t == 2) ? P2LOG2E : NLOG2E;
    P[e] = (_Float16)(v * sc);
}

__global__ __launch_bounds__(512, 2) void lstm_kernel(
    const float* __restrict__ x,          // [B][28][28] fp32
    const _Float16* __restrict__ P,       // packed weights, 160 KB
    const float* __restrict__ Wfc,        // [10][128]
    const float* __restrict__ b_fc,       // [10]
    float* __restrict__ out)              // [B][10]
{
    // Double-buffered A-fragments: frag[buf][kc][slot][j]; slot == reading lane
    __shared__ __align__(16) _Float16 frag[2][NKC][64][8];     // 10 KB
    __shared__ __align__(16) _Float16 Plds[4][8][64][8];       // 32 KB (kc=4 B-frags)
    __shared__ __align__(16) float hplain[TILE_B][HDIM + 4];   // 8.25 KB

    const int tid = threadIdx.x;
    const int l   = tid & 63;
    const int w   = tid >> 6;                  // wave 0..7
    const int b0  = blockIdx.x * TILE_B;

    // ---- stage B-frags for kc=4 into LDS (2048 float4) ----
    {
        const float4* P4 = (const float4*)P;
        float4* dst = (float4*)Plds;
        #pragma unroll
        for (int q = 0; q < 4; ++q)
            dst[tid + q * 512] = P4[8192 + tid + q * 512];
    }
    // ---- resident B-frags for kc=0..3 (parked in AGPRs) ----
    half8 breg[4][4];
    {
        const half8* Pp = (const half8*)P;
        #pragma unroll
        for (int kc = 0; kc < 4; ++kc)
            #pragma unroll
            for (int t4 = 0; t4 < 4; ++t4)
                breg[t4][kc] = Pp[((kc * 4 + t4) * 8 + w) * 64 + l];
    }

    // ---- init LDS: zero h chunks of buf0; bias-1.0 column in BOTH buffers ----
    if (tid < 256) {                           // chunks 0..3 of buf0 = 256 float4
        float4 z = {0.f, 0.f, 0.f, 0.f};
        ((float4*)&frag[0][0][0][0])[tid] = z;
    }
    if (tid < 32) {   // k=156 -> 1.0, k=157..159 -> 0 (slots 48..63, j=4..7)
        int b = tid >> 4, i = tid & 15;
        half4 onev = {(_Float16)1.f, (_Float16)0.f, (_Float16)0.f, (_Float16)0.f};
        *(half4*)&frag[b][4][48 + i][4] = onev;
    }

    // x loaders: 14 lanes in EVERY wave (balanced) -> 8*14 = 112 float4
    const bool isldr = (l < 14);
    const int  lj    = w * 14 + l;             // 0..111
    const int  xr    = lj / 7, xg = lj % 7;    // row 0..15, float4 group 0..6
    const int  xslot = xr + 16 * (xg >> 1);
    const int  xoff  = (xg & 1) * 4;

    // ---- stage x_0 -> buf0.ch4 and x_1 -> buf1.ch4 (prologue commits) ----
    if (isldr) {
        const float4* xs = (const float4*)(x + (size_t)(b0 + xr) * (TSTEPS * IDIM));
        float4 x0 = xs[xg];                    // t=0
        float4 x1 = xs[7 + xg];                // t=1
        half4 h0 = {(_Float16)x0.x, (_Float16)x0.y, (_Float16)x0.z, (_Float16)x0.w};
        half4 h1 = {(_Float16)x1.x, (_Float16)x1.y, (_Float16)x1.z, (_Float16)x1.w};
        *(half4*)&frag[0][4][xslot][xoff] = h0;
        *(half4*)&frag[1][4][xslot][xoff] = h1;
    }

    float cst[4] = {0.f, 0.f, 0.f, 0.f};
    const int u    = w * 16 + (l & 15);
    const int kc_h = w >> 1;                       // u>>5 (wave-uniform)
    const int quad = (2 * w + ((l >> 3) & 1)) & 3; // (u>>3)&3
    const int jh   = l & 7;                        // u&7

    __syncthreads();

    // anti-phase the second co-resident block on each CU (~1600 cyc)
#if __has_builtin(__builtin_amdgcn_s_sleep)
    if (blockIdx.x & 256) __builtin_amdgcn_s_sleep(25);
#endif

    f32x4 acc[4];

    // kc4 partial for a step: acc += x/bias-chunk MFMAs, reading buf `bsel`
    auto kc4_mfma = [&](const _Float16 (*buf)[64][8]) {
        half8 a4 = *(const half8*)&buf[4][l][0];
        #pragma unroll
        for (int t4 = 0; t4 < 4; ++t4) {
            half8 b = *(const half8*)&Plds[t4][w][l][0];
            acc[t4] = __builtin_amdgcn_mfma_f32_16x16x32_f16(a4, b, acc[t4], 0, 0, 0);
        }
    };
    auto zero_acc = [&]() {
        #pragma unroll
        for (int t4 = 0; t4 < 4; ++t4) { f32x4 z = {0.f, 0.f, 0.f, 0.f}; acc[t4] = z; }
    };

    // pre-loop: acc = kc4-part of gates(0)  (x_0 + bias, from buf0.ch4)
    zero_acc();
    kc4_mfma(frag[0]);

    for (int t = 0; t < TSTEPS; ++t) {
        const _Float16 (*cur)[64][8] = frag[t & 1];
        _Float16 (*nxt)[64][8] = frag[(t & 1) ^ 1];
        const bool last = (t == TSTEPS - 1);

        // issue x_{t+2} load now; commit pre-barrier this interval into cur.ch4
        float4 xv;
        const bool doload = (t + 2 < TSTEPS) && isldr;
        if (doload)
            xv = ((const float4*)(x + (size_t)(b0 + xr) * (TSTEPS * IDIM)))[(t + 2) * 7 + xg];

        // kc0-3: the h-dependent MFMAs (post-barrier critical path)
        half8 a[4];
        #pragma unroll
        for (int kc = 0; kc < 4; ++kc)
            a[kc] = *(const half8*)&cur[kc][l][0];
        #pragma unroll
        for (int t4 = 0; t4 < 4; ++t4)
            #pragma unroll
            for (int kc = 0; kc < 4; ++kc)
                acc[t4] = __builtin_amdgcn_mfma_f32_16x16x32_f16(a[kc], breg[t4][kc], acc[t4], 0, 0, 0);

        // activations (scales pre-folded: i,f,o hold -x*log2e; g holds 2x*log2e)
        float hv[4];
        #pragma unroll
        for (int r = 0; r < 4; ++r) {
            float Ei = EXP2F(acc[0][r]);     // e^{-i}
            float Ef = EXP2F(acc[1][r]);     // e^{-f}
            float Eg = EXP2F(acc[2][r]);     // e^{2g}
            float Eo = EXP2F(acc[3][r]);     // e^{-o}
            float Di = 1.f + Ei, Df = 1.f + Ef, Dg = 1.f + Eg, Do = 1.f + Eo;
            float Rif = RCPF(Di * Df);
            float Rgo = RCPF(Dg * Do);
            float is = Rif * Df, fs = Rif * Di;
            float gt = 1.f - 2.f * (Rgo * Do);
            float os = Rgo * Dg;
            float c  = fs * cst[r] + is * gt;
            cst[r] = c;
            float tc = 1.f - 2.f * RCPF(1.f + EXP2F(c * P2LOG2E));
            hv[r] = os * tc;
        }

        // acc is dead now: re-init and issue kc4(t+1) pre-barrier (reads nxt.ch4,
        // whose x_{t+1} was committed >=1 barrier ago). Fills MFMA pipe under act.
        if (!last) {
            zero_acc();
            kc4_mfma(nxt);
        }

        // commit h(t) -> nxt h-chunks; x_{t+2} -> cur.ch4 (read next at t+2 pre-phase)
        #pragma unroll
        for (int r = 0; r < 4; ++r) {
            int m = ((l >> 4) << 2) + r;
            nxt[kc_h][m + 16 * quad][jh] = (_Float16)hv[r];
            if (last) hplain[m][u] = hv[r];
        }
        if (doload) {
            half4 hc = {(_Float16)xv.x, (_Float16)xv.y, (_Float16)xv.z, (_Float16)xv.w};
            *(half4*)&((_Float16 (*)[64][8])cur)[4][xslot][xoff] = hc;
        }
        __syncthreads();
    }

    // ---- FC + ReLU epilogue ----
    if (tid < TILE_B * CDIM) {
        int row = tid / CDIM, c = tid % CDIM;
        const float4* hv4 = (const float4*)&hplain[row][0];
        const float4* wf  = (const float4*)(Wfc + c * HDIM);
        float s = b_fc[c];
        #pragma unroll
        for (int q = 0; q < 32; ++q) {
            float4 a4 = hv4[q], b4 = wf[q];
            s += a4.x * b4.x + a4.y * b4.y + a4.z * b4.z + a4.w * b4.w;
        }
        out[(size_t)(b0 + row) * CDIM + c] = fmaxf(s, 0.f);
    }
}

extern "C" void kernel_launch(void* const* d_in, const int* in_sizes, int n_in,
                              void* d_out, int out_size, void* d_ws, size_t ws_size,
                              hipStream_t stream) {
    const float* x   = (const float*)d_in[0];
    const float* Wih = (const float*)d_in[1];
    const float* Whh = (const float*)d_in[2];
    const float* bih = (const float*)d_in[3];
    const float* bhh = (const float*)d_in[4];
    const float* Wfc = (const float*)d_in[5];
    const float* bfc = (const float*)d_in[6];
    float* out = (float*)d_out;
    _Float16* P = (_Float16*)d_ws;     // 160 KB packed weights

    hipLaunchKernelGGL(pack_w, dim3(320), dim3(256), 0, stream, Wih, Whh, bih, bhh, P);
    hipLaunchKernelGGL(lstm_kernel, dim3(8192 / TILE_B), dim3(512), 0, stream,
                       x, P, Wfc, bfc, out);
}

// Round 10
// 123.891 us; speedup vs baseline: 1.0680x; 1.0680x over previous
//
#include <hip/hip_runtime.h>
#include <math.h>

typedef __attribute__((ext_vector_type(8))) _Float16 half8;
typedef __attribute__((ext_vector_type(4))) _Float16 half4;
typedef __attribute__((ext_vector_type(4))) float    f32x4;
typedef __attribute__((ext_vector_type(2))) float    f32x2;

#define TSTEPS 28
#define IDIM   28
#define HDIM   128
#define NKC    5       // K chunks of 32: 160 = 128 (h) + 28 (x) + bias(1) + 3 pad
#define TILE_B 16
#define CDIM   10

#if __has_builtin(__builtin_amdgcn_exp2f)
#define EXP2F(x) __builtin_amdgcn_exp2f(x)
#else
#define EXP2F(x) exp2f(x)
#endif
#if __has_builtin(__builtin_amdgcn_rcpf)
#define RCPF(x) __builtin_amdgcn_rcpf(x)
#else
#define RCPF(x) (1.0f / (x))
#endif

#define NLOG2E (-1.44269504f)
#define P2LOG2E (2.88539008f)

// P[kc][t][w][lane][j] (f16): B-fragment order for mfma_f32_16x16x32_f16.
// Activation scales folded (i,f,o x -log2e; g x 2log2e). Bias row at k=156
// (pairs with constant 1.0 in A column 156). k=157..159 zero.
__global__ __launch_bounds__(256) void pack_w(const float* __restrict__ Wih,
                                              const float* __restrict__ Whh,
                                              const float* __restrict__ bih,
                                              const float* __restrict__ bhh,
                                              _Float16* __restrict__ P) {
    int e = blockIdx.x * 256 + threadIdx.x;      // 5*4*8*64*8 = 81920
    if (e >= NKC * 4 * 8 * 64 * 8) return;
    int j  = e & 7;
    int ln = (e >> 3) & 63;
    int w  = (e >> 9) & 7;
    int t  = (e >> 12) & 3;
    int kc = e >> 14;
    int k  = kc * 32 + ((ln >> 4) << 3) + j;
    int u  = w * 16 + (ln & 15);
    int g  = t * HDIM + u;
    float v = 0.f;
    if (k < HDIM)                   v = Whh[g * HDIM + k];
    else if (k < HDIM + IDIM)       v = Wih[g * IDIM + (k - HDIM)];
    else if (k == HDIM + IDIM)      v = bih[g] + bhh[g];   // bias row
    float sc = (t == 2) ? P2LOG2E : NLOG2E;
    P[e] = (_Float16)(v * sc);
}

__global__ __launch_bounds__(512, 2) void lstm_kernel(
    const float* __restrict__ x,          // [B][28][28] fp32
    const _Float16* __restrict__ P,       // packed weights, 160 KB
    const float* __restrict__ Wfc,        // [10][128]
    const float* __restrict__ b_fc,       // [10]
    float* __restrict__ out)              // [B][10]
{
    // Double-buffered A-fragments: frag[buf][kc][slot][j]; slot == reading lane
    __shared__ __align__(16) _Float16 frag[2][NKC][64][8];     // 10 KB
    __shared__ __align__(16) _Float16 Plds[4][8][64][8];       // 32 KB (kc=4 B-frags)
    __shared__ __align__(16) float hplain[TILE_B][HDIM + 4];   // 8.25 KB

    const int tid = threadIdx.x;
    const int l   = tid & 63;
    const int w   = tid >> 6;                  // wave 0..7
    const int b0  = blockIdx.x * TILE_B;

    // ---- stage B-frags for kc=4 into LDS (2048 float4) ----
    {
        const float4* P4 = (const float4*)P;
        float4* dst = (float4*)Plds;
        #pragma unroll
        for (int q = 0; q < 4; ++q)
            dst[tid + q * 512] = P4[8192 + tid + q * 512];
    }
    // ---- resident B-frags for kc=0..3 (parked in AGPRs) ----
    half8 breg[4][4];
    {
        const half8* Pp = (const half8*)P;
        #pragma unroll
        for (int kc = 0; kc < 4; ++kc)
            #pragma unroll
            for (int t4 = 0; t4 < 4; ++t4)
                breg[t4][kc] = Pp[((kc * 4 + t4) * 8 + w) * 64 + l];
    }

    // ---- init LDS: zero h chunks of buf0; bias-1.0 column in BOTH buffers ----
    if (tid < 256) {                           // chunks 0..3 of buf0 = 256 float4
        float4 z = {0.f, 0.f, 0.f, 0.f};
        ((float4*)&frag[0][0][0][0])[tid] = z;
    }
    if (tid < 32) {   // k=156 -> 1.0, k=157..159 -> 0 (slots 48..63, j=4..7)
        int b = tid >> 4, i = tid & 15;
        half4 onev = {(_Float16)1.f, (_Float16)0.f, (_Float16)0.f, (_Float16)0.f};
        *(half4*)&frag[b][4][48 + i][4] = onev;
    }
    // ---- stage x_0 -> buf0.ch4 and x_1 -> buf1.ch4 (loaders: waves 0-1) ----
    const int xrow = tid / 7, xg = tid % 7;
    const int xslot = (tid < 112) ? (xrow + 16 * (xg >> 1)) : 0;
    const int xoff  = (xg & 1) * 4;
    if (tid < 112) {
        const float4* xs = (const float4*)(x + (size_t)(b0 + xrow) * (TSTEPS * IDIM));
        float4 x0 = xs[xg];
        float4 x1 = xs[7 + xg];
        half4 h0 = {(_Float16)x0.x, (_Float16)x0.y, (_Float16)x0.z, (_Float16)x0.w};
        half4 h1 = {(_Float16)x1.x, (_Float16)x1.y, (_Float16)x1.z, (_Float16)x1.w};
        *(half4*)&frag[0][4][xslot][xoff] = h0;
        *(half4*)&frag[1][4][xslot][xoff] = h1;
    }

    f32x2 cst01 = {0.f, 0.f}, cst23 = {0.f, 0.f};
    const int u    = w * 16 + (l & 15);
    const int kc_h = w >> 1;                       // u>>5 (wave-uniform)
    const int quad = (2 * w + ((l >> 3) & 1)) & 3; // (u>>3)&3
    const int jh   = l & 7;                        // u&7
    const int mb   = (l >> 4) << 2;                // row base for this lane

    __syncthreads();

    // anti-phase the second co-resident block on each CU (~2048 cyc)
#if __has_builtin(__builtin_amdgcn_s_sleep)
    if (blockIdx.x & 256) __builtin_amdgcn_s_sleep(32);
#endif

    f32x4 acc[4];
    auto zero_acc = [&]() {
        #pragma unroll
        for (int t4 = 0; t4 < 4; ++t4) { f32x4 z = {0.f, 0.f, 0.f, 0.f}; acc[t4] = z; }
    };
    // kc4 (x+bias) MFMAs for a buffer, from a preloaded A-frag
    auto kc4_mfma = [&](half8 a4) {
        #pragma unroll
        for (int t4 = 0; t4 < 4; ++t4) {
            half8 b = *(const half8*)&Plds[t4][w][l][0];
            acc[t4] = __builtin_amdgcn_mfma_f32_16x16x32_f16(a4, b, acc[t4], 0, 0, 0);
        }
    };

    // pre-loop: acc = kc4-part of gates(0)  (x_0 + bias, from buf0.ch4)
    zero_acc();
    kc4_mfma(*(const half8*)&frag[0][4][l][0]);

    for (int t = 0; t < TSTEPS; ++t) {
        const _Float16 (*cur)[64][8] = frag[t & 1];
        _Float16 (*nxt)[64][8] = frag[(t & 1) ^ 1];
        const bool last   = (t == TSTEPS - 1);
        const bool doload = (t + 2 < TSTEPS) && (tid < 112);

        // loaders: issue x_{t+2}; commit into cur.ch4 at interval end
        float4 xv;
        if (doload)
            xv = ((const float4*)(x + (size_t)(b0 + xrow) * (TSTEPS * IDIM)))[(t + 2) * 7 + xg];

        // h-dependent MFMAs (post-barrier critical path): 4 reads + 16 MFMA
        half8 a[4];
        #pragma unroll
        for (int kc = 0; kc < 4; ++kc)
            a[kc] = *(const half8*)&cur[kc][l][0];
        #pragma unroll
        for (int t4 = 0; t4 < 4; ++t4)
            #pragma unroll
            for (int kc = 0; kc < 4; ++kc)
                acc[t4] = __builtin_amdgcn_mfma_f32_16x16x32_f16(a[kc], breg[t4][kc], acc[t4], 0, 0, 0);

        // early-issue next step's kc4 A-frag read (latency hides under act)
        half8 a4n;
        if (!last) a4n = *(const half8*)&nxt[4][l][0];

        // activations over r-pairs (float2 -> v_pk_*_f32); scales pre-folded
        float hv[4];
        #pragma unroll
        for (int rp = 0; rp < 2; ++rp) {
            const int r0 = rp * 2, r1 = r0 + 1;
            f32x2 Ei = {EXP2F(acc[0][r0]), EXP2F(acc[0][r1])};   // e^{-i}
            f32x2 Ef = {EXP2F(acc[1][r0]), EXP2F(acc[1][r1])};   // e^{-f}
            f32x2 Eg = {EXP2F(acc[2][r0]), EXP2F(acc[2][r1])};   // e^{2g}
            f32x2 Eo = {EXP2F(acc[3][r0]), EXP2F(acc[3][r1])};   // e^{-o}
            f32x2 one = {1.f, 1.f};
            f32x2 Di = Ei + one, Df = Ef + one, Dg = Eg + one, Do = Eo + one;
            f32x2 Pif = Di * Df, Pgo = Dg * Do;
            f32x2 Rif = {RCPF(Pif.x), RCPF(Pif.y)};
            f32x2 Rgo = {RCPF(Pgo.x), RCPF(Pgo.y)};
            f32x2 is = Rif * Df, fs = Rif * Di;
            f32x2 gt = one - 2.f * (Rgo * Do);
            f32x2 os = Rgo * Dg;
            f32x2 cstp = rp ? cst23 : cst01;
            f32x2 c = fs * cstp + is * gt;
            if (rp) cst23 = c; else cst01 = c;
            f32x2 Etc = {EXP2F(c.x * P2LOG2E), EXP2F(c.y * P2LOG2E)};
            f32x2 Dtc = Etc + one;
            f32x2 Rtc = {RCPF(Dtc.x), RCPF(Dtc.y)};
            f32x2 tc = one - 2.f * Rtc;
            f32x2 h2 = os * tc;
            hv[r0] = h2.x; hv[r1] = h2.y;
        }

        // commit h(t) -> nxt h-chunks
        #pragma unroll
        for (int r = 0; r < 4; ++r) {
            nxt[kc_h][mb + r + 16 * quad][jh] = (_Float16)hv[r];
            if (last) hplain[mb + r][u] = hv[r];
        }

        // acc is dead: re-init and run kc4(t+1) MFMAs (issue-only tail)
        if (!last) {
            zero_acc();
            kc4_mfma(a4n);
        }
        // loaders commit x_{t+2} -> cur.ch4 (next read: interval t+1's kc4(t+2))
        if (doload) {
            half4 hc = {(_Float16)xv.x, (_Float16)xv.y, (_Float16)xv.z, (_Float16)xv.w};
            *(half4*)&((_Float16 (*)[64][8])cur)[4][xslot][xoff] = hc;
        }
        __syncthreads();
    }

    // ---- FC + ReLU epilogue ----
    if (tid < TILE_B * CDIM) {
        int row = tid / CDIM, c = tid % CDIM;
        const float4* hv4 = (const float4*)&hplain[row][0];
        const float4* wf  = (const float4*)(Wfc + c * HDIM);
        float s = b_fc[c];
        #pragma unroll
        for (int q = 0; q < 32; ++q) {
            float4 a4 = hv4[q], b4 = wf[q];
            s += a4.x * b4.x + a4.y * b4.y + a4.z * b4.z + a4.w * b4.w;
        }
        out[(size_t)(b0 + row) * CDIM + c] = fmaxf(s, 0.f);
    }
}

extern "C" void kernel_launch(void* const* d_in, const int* in_sizes, int n_in,
                              void* d_out, int out_size, void* d_ws, size_t ws_size,
                              hipStream_t stream) {
    const float* x   = (const float*)d_in[0];
    const float* Wih = (const float*)d_in[1];
    const float* Whh = (const float*)d_in[2];
    const float* bih = (const float*)d_in[3];
    const float* bhh = (const float*)d_in[4];
    const float* Wfc = (const float*)d_in[5];
    const float* bfc = (const float*)d_in[6];
    float* out = (float*)d_out;
    _Float16* P = (_Float16*)d_ws;     // 160 KB packed weights

    hipLaunchKernelGGL(pack_w, dim3(320), dim3(256), 0, stream, Wih, Whh, bih, bhh, P);
    hipLaunchKernelGGL(lstm_kernel, dim3(8192 / TILE_B), dim3(512), 0, stream,
                       x, P, Wfc, bfc, out);
}